// Round 1
// baseline (1527.193 us; speedup 1.0000x reference)
//
#include <hip/hip_runtime.h>

typedef _Float16 half8 __attribute__((ext_vector_type(8)));
typedef float floatx4 __attribute__((ext_vector_type(4)));

#define Bsz 512
#define Tsz 168
#define Fsz 16
#define Hsz 256
#define KTILES 9      // K = 288 = 9 * 32  (256 h + 16 x + 16 zero pad)
#define LDS_K 296     // padded LDS row stride in halves

// workspace layout (bytes, all 16B aligned)
#define WSW_OFF   0          // swizzled [w_hh|w_ih|0] f16 frags: 64nt*9kt*64lane*16B = 589824
#define BIAS_OFF  589824     // reordered (b_ih+b_hh) fp32: 1024*4 = 4096
#define FC1_OFF   593920     // fc1 frags: 8nt*8kt*64*16B = 65536
#define FC2_OFF   659456     // fc2 frags: 4nt*4kt*64*16B = 16384
#define HH_OFF    675840     // h history f16 [B][T][H]: 512*168*256*2 = 44040192

// ---------------- prep: swizzle recurrent weights into MFMA B-frag order ----
// N-tile ordering: nt -> j-block J = nt>>2, gate g = nt&3 (torch i,f,g,o)
// B-frag: lane = n_in + 16*kg holds B[k = kt*32 + kg*8 + e][n], e=0..7
__global__ void k_swz_whh(const float* __restrict__ w_hh,
                          const float* __restrict__ w_ih,
                          _Float16* __restrict__ wsw) {
    int tile = blockIdx.x;            // nt*9 + kt, 576 tiles
    int nt = tile / KTILES, kt = tile - nt * KTILES;
    int lane = threadIdx.x;           // 64
    int n_in = lane & 15, kg = lane >> 4;
    int J = nt >> 2, g = nt & 3;
    int n_orig = g * 256 + J * 16 + n_in;
    half8 v;
#pragma unroll
    for (int e = 0; e < 8; ++e) {
        int k = kt * 32 + kg * 8 + e;
        float f;
        if (k < 256)      f = w_hh[n_orig * 256 + k];
        else if (k < 272) f = w_ih[n_orig * 16 + (k - 256)];
        else              f = 0.0f;
        v[e] = (_Float16)f;
    }
    ((half8*)wsw)[tile * 64 + lane] = v;
}

__global__ void k_bias(const float* __restrict__ b_ih,
                       const float* __restrict__ b_hh,
                       float* __restrict__ bias) {
    int id = blockIdx.x * 256 + threadIdx.x;   // 1024
    int nt = id >> 4, n = id & 15;
    int J = nt >> 2, g = nt & 3;
    int n_orig = g * 256 + J * 16 + n;
    bias[id] = b_ih[n_orig] + b_hh[n_orig];
}

// generic fc swizzle: W[N][K] row-major -> frag tiles, nt ordering plain
__global__ void k_swz_fc(const float* __restrict__ w, _Float16* __restrict__ dst,
                         int ktiles, int K) {
    int tile = blockIdx.x;
    int nt = tile / ktiles, kt = tile - nt * ktiles;
    int lane = threadIdx.x;
    int n_in = lane & 15, kg = lane >> 4;
    int n_orig = nt * 16 + n_in;
    half8 v;
#pragma unroll
    for (int e = 0; e < 8; ++e) {
        int k = kt * 32 + kg * 8 + e;
        v[e] = (_Float16)w[n_orig * K + k];
    }
    ((half8*)dst)[tile * 64 + lane] = v;
}

// ---------------- recurrent LSTM: 32 WGs x 16 batch rows, t-loop inside ----
__global__ __launch_bounds__(512) void k_lstm(
    const float* __restrict__ x, const _Float16* __restrict__ wsw,
    const float* __restrict__ bias, _Float16* __restrict__ hh) {
    __shared__ _Float16 h_lds[16][LDS_K];   // [m][k]: h(0..255) | x(256..271) | 0(272..287)

    const int tid = threadIdx.x;
    const int wave = tid >> 6, lane = tid & 63;
    const int n_in = lane & 15, quad = lane >> 4;
    const int b0 = blockIdx.x * 16;

    // zero LDS (h0 = 0, pad = 0)
    for (int i = tid; i < 16 * LDS_K; i += 512)
        ((_Float16*)h_lds)[i] = (_Float16)0.0f;

    // per-lane biases for this wave's 8 N-tiles (nt_local = jb*4 + gate)
    float bs[8];
#pragma unroll
    for (int q = 0; q < 8; ++q)
        bs[q] = bias[(wave * 8 + q) * 16 + n_in];

    float c_st[2][4] = {{0.f,0.f,0.f,0.f},{0.f,0.f,0.f,0.f}};
    const half8* wf = (const half8*)wsw;

    __syncthreads();

    for (int t = 0; t < Tsz; ++t) {
        // stage x_t as f16 into augmented-K region
        if (tid < 256) {
            int m = tid >> 4, f = tid & 15;
            h_lds[m][256 + f] = (_Float16)x[((b0 + m) * Tsz + t) * Fsz + f];
        }
        __syncthreads();   // h_t (written end of prev iter) + x_t visible

        // A fragments: A[m][k], m = n_in, k = kt*32 + quad*8 + e
        half8 afr[KTILES];
#pragma unroll
        for (int kt = 0; kt < KTILES; ++kt)
            afr[kt] = *(const half8*)&h_lds[n_in][kt * 32 + quad * 8];
        __syncthreads();   // all reads done before anyone writes h_{t+1}

        floatx4 acc[8];
#pragma unroll
        for (int q = 0; q < 8; ++q) acc[q] = (floatx4){0.f, 0.f, 0.f, 0.f};

#pragma unroll
        for (int q = 0; q < 8; ++q) {
            const int base = (wave * 8 + q) * KTILES * 64 + lane;
#pragma unroll
            for (int kt = 0; kt < KTILES; ++kt) {
                half8 bfr = wf[base + kt * 64];
                acc[q] = __builtin_amdgcn_mfma_f32_16x16x32_f16(afr[kt], bfr, acc[q], 0, 0, 0);
            }
        }

        // cell update; D layout: col n = n_in, row m = quad*4 + r  [verified m89/m91]
#pragma unroll
        for (int jb = 0; jb < 2; ++jb) {
            const int j = (wave * 2 + jb) * 16 + n_in;
#pragma unroll
            for (int r = 0; r < 4; ++r) {
                const int m = quad * 4 + r;
                float ig = acc[jb * 4 + 0][r] + bs[jb * 4 + 0];
                float fg = acc[jb * 4 + 1][r] + bs[jb * 4 + 1];
                float gg = acc[jb * 4 + 2][r] + bs[jb * 4 + 2];
                float og = acc[jb * 4 + 3][r] + bs[jb * 4 + 3];
                float si = 1.0f / (1.0f + __expf(-ig));
                float sf = 1.0f / (1.0f + __expf(-fg));
                float tg = 1.0f - 2.0f / (__expf(2.0f * gg) + 1.0f);
                float so = 1.0f / (1.0f + __expf(-og));
                float c = sf * c_st[jb][r] + si * tg;
                c_st[jb][r] = c;
                float th = 1.0f - 2.0f / (__expf(2.0f * c) + 1.0f);
                _Float16 hv = (_Float16)(so * th);
                h_lds[m][j] = hv;                                   // h_{t+1} for next step
                hh[((size_t)(b0 + m) * Tsz + t) * Hsz + j] = hv;    // scan output at t
            }
        }
    }
}

// ---------------- MLP head: 64 tokens/WG (4 waves x 16), MFMA f16 ----------
__global__ __launch_bounds__(256) void k_mlp(
    const _Float16* __restrict__ hh, const _Float16* __restrict__ w1f,
    const _Float16* __restrict__ w2f, const float* __restrict__ b1,
    const float* __restrict__ b2, const float* __restrict__ w3,
    const float* __restrict__ b3, float* __restrict__ out) {
    __shared__ _Float16 st1[4][16][136];
    __shared__ _Float16 st2[4][16][72];

    const int tid = threadIdx.x;
    const int wave = tid >> 6, lane = tid & 63;
    const int n_in = lane & 15, quad = lane >> 4;
    const int tok0 = blockIdx.x * 64 + wave * 16;

    // fc1: [16 tok x 256] @ w1^T -> [16 x 128]
    half8 afr[8];
#pragma unroll
    for (int kt = 0; kt < 8; ++kt)
        afr[kt] = *(const half8*)&hh[(size_t)(tok0 + n_in) * 256 + kt * 32 + quad * 8];
    const half8* w1 = (const half8*)w1f;
#pragma unroll
    for (int nt = 0; nt < 8; ++nt) {
        floatx4 a = (floatx4){0.f, 0.f, 0.f, 0.f};
#pragma unroll
        for (int kt = 0; kt < 8; ++kt)
            a = __builtin_amdgcn_mfma_f32_16x16x32_f16(afr[kt], w1[(nt * 8 + kt) * 64 + lane], a, 0, 0, 0);
        float bb = b1[nt * 16 + n_in];
#pragma unroll
        for (int r = 0; r < 4; ++r) {
            float v = a[r] + bb;
            st1[wave][quad * 4 + r][nt * 16 + n_in] = (_Float16)(v > 0.f ? v : 0.f);
        }
    }
    __syncthreads();

    // fc2: [16 x 128] @ w2^T -> [16 x 64]
    half8 a2[4];
#pragma unroll
    for (int kt = 0; kt < 4; ++kt)
        a2[kt] = *(const half8*)&st1[wave][n_in][kt * 32 + quad * 8];
    const half8* w2 = (const half8*)w2f;
#pragma unroll
    for (int nt = 0; nt < 4; ++nt) {
        floatx4 a = (floatx4){0.f, 0.f, 0.f, 0.f};
#pragma unroll
        for (int kt = 0; kt < 4; ++kt)
            a = __builtin_amdgcn_mfma_f32_16x16x32_f16(a2[kt], w2[(nt * 4 + kt) * 64 + lane], a, 0, 0, 0);
        float bb = b2[nt * 16 + n_in];
#pragma unroll
        for (int r = 0; r < 4; ++r) {
            float v = a[r] + bb;
            st2[wave][quad * 4 + r][nt * 16 + n_in] = (_Float16)(v > 0.f ? v : 0.f);
        }
    }
    __syncthreads();

    // fc3: [16 x 64] @ w3 -> [16]; lane (n_in=token m, quad=k-quarter)
    float p = 0.0f;
#pragma unroll
    for (int e = 0; e < 16; ++e)
        p += (float)st2[wave][n_in][quad * 16 + e] * w3[quad * 16 + e];
    p += __shfl_down(p, 32);
    p += __shfl_down(p, 16);
    if (quad == 0) out[tok0 + n_in] = p + b3[0];
}

extern "C" void kernel_launch(void* const* d_in, const int* in_sizes, int n_in,
                              void* d_out, int out_size, void* d_ws, size_t ws_size,
                              hipStream_t stream) {
    const float* x     = (const float*)d_in[0];
    const float* w_ih  = (const float*)d_in[1];
    const float* w_hh  = (const float*)d_in[2];
    const float* b_ih  = (const float*)d_in[3];
    const float* b_hh  = (const float*)d_in[4];
    const float* fc1_w = (const float*)d_in[5];
    const float* fc1_b = (const float*)d_in[6];
    const float* fc2_w = (const float*)d_in[7];
    const float* fc2_b = (const float*)d_in[8];
    const float* fc3_w = (const float*)d_in[9];
    const float* fc3_b = (const float*)d_in[10];

    char* ws = (char*)d_ws;
    _Float16* wsw  = (_Float16*)(ws + WSW_OFF);
    float*    bias = (float*)(ws + BIAS_OFF);
    _Float16* w1f  = (_Float16*)(ws + FC1_OFF);
    _Float16* w2f  = (_Float16*)(ws + FC2_OFF);
    _Float16* hhist= (_Float16*)(ws + HH_OFF);

    k_swz_whh<<<576, 64, 0, stream>>>(w_hh, w_ih, wsw);
    k_bias<<<4, 256, 0, stream>>>(b_ih, b_hh, bias);
    k_swz_fc<<<64, 64, 0, stream>>>(fc1_w, w1f, 8, 256);
    k_swz_fc<<<16, 64, 0, stream>>>(fc2_w, w2f, 4, 128);
    k_lstm<<<32, 512, 0, stream>>>(x, wsw, bias, hhist);
    k_mlp<<<Bsz * Tsz / 64, 256, 0, stream>>>(hhist, w1f, w2f, fc1_b, fc2_b,
                                              fc3_w, fc3_b, (float*)d_out);
}